// Round 5
// baseline (1584.916 us; speedup 1.0000x reference)
//
#include <hip/hip_runtime.h>
#include <math.h>

// NeuralStateSpace: h_{t+1} = tanh(h_t @ A_w^T + A_b + x_t @ B_w^T + B_b), then LN + head.
// One workgroup per batch element (256 blocks -> 256 CUs), 256 threads (4 waves).
// R=4 row-reuse: thread owns rows {g,g+32,g+64,g+96} x 16-wide h-slice -> LDS
// lane-bytes drop 4x vs R=1 (LDS delivery was the R3 bottleneck: 98KB/step ~= 768cyc).
// Reduction across the 8 slice-threads is pure DPP: partners at lane xor {1,2,8}
// (quad_perm 0xB1, 0x4E, row_ror:8). h stored XOR-swizzled so the 8 distinct
// float4 addresses per read inst span all 32 banks. Weights in registers
// (constant-trip unrolled loops -> compile-time indices). tanh = 1-2/(2^acc+1)
// with weights pre-scaled by 2*log2(e) (self-saturating, no clamp).

#define S_LEN   4096
#define I_DIM   64
#define H_DIM   128
#define T_CHUNK 64
#define NCHUNK  (S_LEN / T_CHUNK)   // 64
#define NTHR    256
#define KSCALE  2.8853900817779268f  // 2*log2(e)

typedef float v2f __attribute__((ext_vector_type(2)));

static __device__ __forceinline__ v2f pk_mul(v2f a, v2f b) {
    v2f d; asm("v_pk_mul_f32 %0, %1, %2" : "=v"(d) : "v"(a), "v"(b)); return d;
}
static __device__ __forceinline__ v2f pk_fma(v2f a, v2f b, v2f c) {
    v2f d; asm("v_pk_fma_f32 %0, %1, %2, %3" : "=v"(d) : "v"(a), "v"(b), "v"(c)); return d;
}
static __device__ __forceinline__ v2f lo4(float4 v) { v2f r; r.x = v.x; r.y = v.y; return r; }
static __device__ __forceinline__ v2f hi4(float4 v) { v2f r; r.x = v.z; r.y = v.w; return r; }

// DPP-permuted copy (ctrl literal): quad_perm xor1=0xB1, xor2=0x4E, row_ror:8=0x128
#define DPPF(v, CTRL) __builtin_bit_cast(float, \
    __builtin_amdgcn_update_dpp(0, __builtin_bit_cast(int, (v)), (CTRL), 0xf, 0xf, true))
#define RED8(s) { s += DPPF(s, 0xB1); s += DPPF(s, 0x4E); s += DPPF(s, 0x128); }

static __device__ __forceinline__ float fast_exp2(float x) {
    float r; asm("v_exp_f32 %0, %1" : "=v"(r) : "v"(x)); return r;
}
static __device__ __forceinline__ float fast_rcp(float x) {
    float r; asm("v_rcp_f32 %0, %1" : "=v"(r) : "v"(x)); return r;
}

__global__ __launch_bounds__(NTHR, 1)
void nss_scan_kernel(const float* __restrict__ x,
                     const float* __restrict__ A_w,
                     const float* __restrict__ A_b,
                     const float* __restrict__ B_w,
                     const float* __restrict__ B_b,
                     const float* __restrict__ ln_g,
                     const float* __restrict__ ln_b,
                     const float* __restrict__ head_w,
                     const float* __restrict__ head_b,
                     float* __restrict__ out)
{
    __shared__ float xs[2][T_CHUNK * I_DIM];  // 32 KiB double-buffered x chunks
    __shared__ float hbuf[2][H_DIM];          // 1 KiB double-buffered h (XOR-swizzled)
    __shared__ float pad[12288];              // 48 KiB: total >80KiB => 1 block/CU

    const int t = threadIdx.x;
    const int b = blockIdx.x;
    const int l = t & 63;                 // lane
    const int w = t >> 6;                 // wave 0..3
    const int pos = l & 15;
    const int row16 = l >> 4;
    const int e   = (pos & 3) | (((pos >> 3) & 1) << 2);  // h-slice 0..7
    const int grp = (pos >> 2) & 1;
    const int g   = w * 8 + row16 * 2 + grp;              // row-group 0..31

    if (b == 0x7fffffff) pad[t] = 0.f;    // keep pad alive (never true)

    // ---- weights into registers (scaled by 2*log2e); constant-trip unrolled ----
    float4 aw[4][4];  // A_w[g+32j][16e + 4k .. +3]
    float4 bw[4][2];  // B_w[g+32j][ 8e + 4k .. +3]
#pragma unroll
    for (int j = 0; j < 4; ++j) {
        const float* Ap = A_w + (g + 32 * j) * H_DIM + 16 * e;
#pragma unroll
        for (int k = 0; k < 4; ++k) {
            float4 v = *(const float4*)(Ap + 4 * k);
            v.x *= KSCALE; v.y *= KSCALE; v.z *= KSCALE; v.w *= KSCALE;
            aw[j][k] = v;
        }
        const float* Bp = B_w + (g + 32 * j) * I_DIM + 8 * e;
#pragma unroll
        for (int k = 0; k < 2; ++k) {
            float4 v = *(const float4*)(Bp + 4 * k);
            v.x *= KSCALE; v.y *= KSCALE; v.z *= KSCALE; v.w *= KSCALE;
            bw[j][k] = v;
        }
    }

    // h read offsets: float4 j=4e+k stored at j^((j>>3)&3)  (banks 0..31 covered)
    int hoff0, hoff1, hoff2, hoff3;
    {
        int j0 = 4 * e + 0; hoff0 = (j0 ^ ((j0 >> 3) & 3)) * 16;
        int j1 = 4 * e + 1; hoff1 = (j1 ^ ((j1 >> 3) & 3)) * 16;
        int j2 = 4 * e + 2; hoff2 = (j2 ^ ((j2 >> 3) & 3)) * 16;
        int j3 = 4 * e + 3; hoff3 = (j3 ^ ((j3 >> 3) & 3)) * 16;
    }

    // writer: lanes pos<8 write row rw = g + 32*(pos&3)
    const bool writer = (pos < 8);
    const int  e_low  = pos & 3;
    const int  rw     = g + 32 * e_low;
    int hwoff;
    {
        int j = rw >> 2, cc = rw & 3;
        int js = j ^ ((j >> 3) & 3);
        hwoff = js * 16 + cc * 4;
    }
    const float bias_w = (A_b[rw] + B_b[rw]) * KSCALE;
    const bool sel1 = (e_low & 1) != 0;
    const bool sel2 = (e_low & 2) != 0;

    if (t < H_DIM) hbuf[0][t] = 0.f;  // zeros: swizzle-invariant

    const float* xb = x + (size_t)b * S_LEN * I_DIM;

    // prologue: stage chunk 0
    {
        const float4* gsrc = (const float4*)xb;
        float4* d = (float4*)xs[0];
#pragma unroll
        for (int rr = 0; rr < 4; ++rr) d[rr * NTHR + t] = gsrc[rr * NTHR + t];
    }
    __syncthreads();

    for (int c = 0; c < NCHUNK; ++c) {
        const int cur = c & 1;
        float4 nx0, nx1, nx2, nx3;
        if (c + 1 < NCHUNK) {
            const float4* gsrc = (const float4*)(xb + (size_t)(c + 1) * T_CHUNK * I_DIM);
            nx0 = gsrc[0 * NTHR + t];
            nx1 = gsrc[1 * NTHR + t];
            nx2 = gsrc[2 * NTHR + t];
            nx3 = gsrc[3 * NTHR + t];
        }
        const char* xbase = (const char*)xs[cur] + 32 * e;

#pragma unroll 2
        for (int ss = 0; ss < T_CHUNK; ++ss) {
            const int p = ss & 1;  // compile-time under unroll-2
            const char* hB   = (const char*)hbuf + p * 512;
            const char* xrow = xbase + ss * 256;

            const float4 h0 = *(const float4*)(hB + hoff0);
            const float4 h1 = *(const float4*)(hB + hoff1);
            const float4 h2 = *(const float4*)(hB + hoff2);
            const float4 h3 = *(const float4*)(hB + hoff3);
            const float4 x0 = *(const float4*)(xrow);
            const float4 x1 = *(const float4*)(xrow + 16);

            float s0, s1, s2, s3;
            {
                v2f a;
#define ROWDOT(j, sj)                                   \
                a = pk_mul(lo4(aw[j][0]), lo4(h0));     \
                a = pk_fma(hi4(aw[j][0]), hi4(h0), a);  \
                a = pk_fma(lo4(aw[j][1]), lo4(h1), a);  \
                a = pk_fma(hi4(aw[j][1]), hi4(h1), a);  \
                a = pk_fma(lo4(aw[j][2]), lo4(h2), a);  \
                a = pk_fma(hi4(aw[j][2]), hi4(h2), a);  \
                a = pk_fma(lo4(aw[j][3]), lo4(h3), a);  \
                a = pk_fma(hi4(aw[j][3]), hi4(h3), a);  \
                a = pk_fma(lo4(bw[j][0]), lo4(x0), a);  \
                a = pk_fma(hi4(bw[j][0]), hi4(x0), a);  \
                a = pk_fma(lo4(bw[j][1]), lo4(x1), a);  \
                a = pk_fma(hi4(bw[j][1]), hi4(x1), a);  \
                sj = a.x + a.y;
                ROWDOT(0, s0)
                ROWDOT(1, s1)
                ROWDOT(2, s2)
                ROWDOT(3, s3)
#undef ROWDOT
            }
            // reduce across the 8 slice-threads (lanes xor 1,2,8): pure DPP
            RED8(s0) RED8(s1) RED8(s2) RED8(s3)

            if (writer) {
                const float v01 = sel1 ? s1 : s0;
                const float v23 = sel1 ? s3 : s2;
                const float v   = sel2 ? v23 : v01;
                const float ex  = fast_exp2(v + bias_w);
                const float th  = fmaf(-2.f, fast_rcp(ex + 1.f), 1.f);  // tanh
                *(float*)((char*)hbuf + (p ^ 1) * 512 + hwoff) = th;
            }
            __syncthreads();
        }

        if (c + 1 < NCHUNK) {
            float4* d = (float4*)xs[cur ^ 1];
            d[0 * NTHR + t] = nx0;
            d[1 * NTHR + t] = nx1;
            d[2 * NTHR + t] = nx2;
            d[3 * NTHR + t] = nx3;
            __syncthreads();
        }
    }

    // ---- epilogue: LayerNorm + head (final h in hbuf[0]; unswizzle on read) ----
    if (t < 64) {
        const float* hf = (const float*)hbuf;
        int ja = t >> 2;          int ca = t & 3;
        int jb = (t + 64) >> 2;   int cb = t & 3;
        const float a  = hf[(ja ^ ((ja >> 3) & 3)) * 4 + ca];
        const float c2 = hf[(jb ^ ((jb >> 3) & 3)) * 4 + cb];
        float sum = a + c2;
#pragma unroll
        for (int o = 32; o > 0; o >>= 1) sum += __shfl_xor(sum, o);
        const float mu = sum * (1.f / 128.f);
        const float d1 = a - mu, d2 = c2 - mu;
        float sq = d1 * d1 + d2 * d2;
#pragma unroll
        for (int o = 32; o > 0; o >>= 1) sq += __shfl_xor(sq, o);
        const float rs = rsqrtf(sq * (1.f / 128.f) + 1e-5f);
        const float hn1 = d1 * rs * ln_g[t] + ln_b[t];
        const float hn2 = d2 * rs * ln_g[t + 64] + ln_b[t + 64];
        float contrib = hn1 * head_w[t] + hn2 * head_w[t + 64];
#pragma unroll
        for (int o = 32; o > 0; o >>= 1) contrib += __shfl_xor(contrib, o);
        if (t == 0) out[b] = contrib + head_b[0];
    }
}

extern "C" void kernel_launch(void* const* d_in, const int* in_sizes, int n_in,
                              void* d_out, int out_size, void* d_ws, size_t ws_size,
                              hipStream_t stream)
{
    const float* x      = (const float*)d_in[0];
    const float* A_w    = (const float*)d_in[1];
    const float* A_b    = (const float*)d_in[2];
    const float* B_w    = (const float*)d_in[3];
    const float* B_b    = (const float*)d_in[4];
    const float* ln_g   = (const float*)d_in[5];
    const float* ln_b   = (const float*)d_in[6];
    const float* head_w = (const float*)d_in[7];
    const float* head_b = (const float*)d_in[8];
    float* out = (float*)d_out;

    const int Bsz = in_sizes[0] / (S_LEN * I_DIM);  // 256
    nss_scan_kernel<<<Bsz, NTHR, 0, stream>>>(x, A_w, A_b, B_w, B_b,
                                              ln_g, ln_b, head_w, head_b, out);
}